// Round 3
// baseline (464.645 us; speedup 1.0000x reference)
//
#include <hip/hip_runtime.h>

typedef float  f32x4  __attribute__((ext_vector_type(4)));
typedef __bf16 bf16x8 __attribute__((ext_vector_type(8)));
typedef __bf16 bf16x4 __attribute__((ext_vector_type(4)));

#define L2EPS   1e-12f
#define SHRINKC 0.0025f

// ---- helpers -------------------------------------------------------------

__device__ __forceinline__ bf16x8 pack_bf16(f32x4 v0, f32x4 v1) {
  bf16x8 r;
  r[0] = (__bf16)v0[0]; r[1] = (__bf16)v0[1]; r[2] = (__bf16)v0[2]; r[3] = (__bf16)v0[3];
  r[4] = (__bf16)v1[0]; r[5] = (__bf16)v1[1]; r[6] = (__bf16)v1[2]; r[7] = (__bf16)v1[3];
  return r;
}

__device__ __forceinline__ bf16x8 load_cvt_bf16x8(const float* p) {
  const f32x4* q = (const f32x4*)p;
  return pack_bf16(q[0], q[1]);
}

__device__ __forceinline__ float dot4(f32x4 v) {
  return v[0]*v[0] + v[1]*v[1] + v[2]*v[2] + v[3]*v[3];
}

// ---- gemm1: h = relu(memory @ w1^T + b1), 32x32 tile / 1-wave block ------
// grid = (16,16), block = 64. Also zeroes attsum (64 floats per block).
__global__ __launch_bounds__(64) void gemm1(
    const float* __restrict__ A, const float* __restrict__ B,
    const float* __restrict__ bias, float* __restrict__ C,
    float* __restrict__ attsum) {
  const int bid = blockIdx.y * gridDim.x + blockIdx.x;  // 0..255
  attsum[bid * 64 + threadIdx.x] = 0.f;

  const int K = 1024, N = 512;
  const int r0   = blockIdx.x * 32;
  const int n0   = blockIdx.y * 32;
  const int lane = threadIdx.x & 63;
  const int quad = lane >> 4;
  const int m    = lane & 15;

  f32x4 acc[2][2] = {};
  for (int k0 = 0; k0 < K; k0 += 32) {
    const int kk = k0 + quad * 8;
    bf16x8 a[2], b[2];
    #pragma unroll
    for (int rg = 0; rg < 2; ++rg)
      a[rg] = load_cvt_bf16x8(A + (size_t)(r0 + rg * 16 + m) * K + kk);
    #pragma unroll
    for (int cf = 0; cf < 2; ++cf)
      b[cf] = load_cvt_bf16x8(B + (size_t)(n0 + cf * 16 + m) * K + kk);
    #pragma unroll
    for (int rg = 0; rg < 2; ++rg)
      #pragma unroll
      for (int cf = 0; cf < 2; ++cf)
        acc[rg][cf] = __builtin_amdgcn_mfma_f32_16x16x32_bf16(a[rg], b[cf], acc[rg][cf], 0, 0, 0);
  }
  #pragma unroll
  for (int rg = 0; rg < 2; ++rg)
    #pragma unroll
    for (int cf = 0; cf < 2; ++cf) {
      const int n = n0 + cf * 16 + m;
      const float bv = bias[n];
      #pragma unroll
      for (int vi = 0; vi < 4; ++vi) {
        const int r = r0 + rg * 16 + quad * 4 + vi;
        C[(size_t)r * N + n] = fmaxf(acc[rg][cf][vi] + bv, 0.f);
      }
    }
}

// ---- gemm2_norm: mp = relu(h @ w2^T + b2); memory_norm = l2norm(mp) ------
// Full-row tiles: grid = 32 (16 rows each), block = 256 (4 waves x 256 cols).
// Writes mnorm fp32 (output 3) + bf16 copy; mp never hits memory.
__global__ __launch_bounds__(256) void gemm2_norm(
    const float* __restrict__ A,    // h: 512 x 512
    const float* __restrict__ B,    // w2: 1024 x 512
    const float* __restrict__ bias, // b2: 1024
    float* __restrict__ mn_f32, __bf16* __restrict__ mn_bf16) {
  const int r0   = blockIdx.x * 16;
  const int wave = threadIdx.x >> 6;
  const int lane = threadIdx.x & 63;
  const int quad = lane >> 4;
  const int m    = lane & 15;
  const int n0   = wave * 256;

  f32x4 acc[16] = {};
  for (int k0 = 0; k0 < 512; k0 += 32) {
    const int kk = k0 + quad * 8;
    const bf16x8 a = load_cvt_bf16x8(A + (size_t)(r0 + m) * 512 + kk);
    #pragma unroll
    for (int cf = 0; cf < 16; ++cf) {
      const bf16x8 b = load_cvt_bf16x8(B + (size_t)(n0 + cf * 16 + m) * 512 + kk);
      acc[cf] = __builtin_amdgcn_mfma_f32_16x16x32_bf16(a, b, acc[cf], 0, 0, 0);
    }
  }
  // bias + relu, per-row sumsq partials (lane holds rows quad*4+vi, 16 cols)
  float ss[4] = {0.f, 0.f, 0.f, 0.f};
  #pragma unroll
  for (int cf = 0; cf < 16; ++cf) {
    const float bv = bias[n0 + cf * 16 + m];
    #pragma unroll
    for (int vi = 0; vi < 4; ++vi) {
      const float v = fmaxf(acc[cf][vi] + bv, 0.f);
      acc[cf][vi] = v;
      ss[vi] += v * v;
    }
  }
  // reduce over the 16 m-lanes within each quad
  #pragma unroll
  for (int vi = 0; vi < 4; ++vi)
    #pragma unroll
    for (int d = 1; d < 16; d <<= 1) ss[vi] += __shfl_xor(ss[vi], d);

  __shared__ float psum[4][16];
  __shared__ float invs[16];
  if (m == 0) {
    #pragma unroll
    for (int vi = 0; vi < 4; ++vi) psum[wave][quad * 4 + vi] = ss[vi];
  }
  __syncthreads();
  if (threadIdx.x < 16) {
    const float t = psum[0][threadIdx.x] + psum[1][threadIdx.x] +
                    psum[2][threadIdx.x] + psum[3][threadIdx.x];
    invs[threadIdx.x] = 1.f / fmaxf(sqrtf(t), L2EPS);
  }
  __syncthreads();
  #pragma unroll
  for (int vi = 0; vi < 4; ++vi) {
    const int r = r0 + quad * 4 + vi;
    const float iv = invs[quad * 4 + vi];
    #pragma unroll
    for (int cf = 0; cf < 16; ++cf) {
      const int n = n0 + cf * 16 + m;
      const float o = acc[cf][vi] * iv;
      mn_f32[(size_t)r * 1024 + n] = o;
      mn_bf16[(size_t)r * 1024 + n] = (__bf16)o;
    }
  }
}

// ---- fused attention: copies x -> input_flat, computes row norms inline,
//      scores -> softmax -> shrink -> renorm -> att/output/attsum ----------
// grid = 512 (32 rows each), block = 256 (4 waves; wave w owns cols w*128..)
__global__ __launch_bounds__(256) void attend(
    const float* __restrict__ x, const __bf16* __restrict__ Mn,
    const float* __restrict__ Mnf, float* __restrict__ out_flat,
    float* __restrict__ out_out, float* __restrict__ out_att,
    float* __restrict__ attsum) {
  __shared__ float S[32][512];  // 64 KB
  __shared__ float invn[32];
  const int r0   = blockIdx.x * 32;
  const int tid  = threadIdx.x;
  const int wave = tid >> 6;
  const int lane = tid & 63;
  const int quad = lane >> 4;
  const int m    = lane & 15;
  const int n0w  = wave * 128;

  float ss0 = 0.f, ss1 = 0.f;
  f32x4 acc[8][2] = {};
  for (int k0 = 0; k0 < 1024; k0 += 32) {
    const int kk = k0 + quad * 8;
    bf16x8 a[2];
    f32x4 v0a, v0b, v1a, v1b;
    {
      const int row = r0 + m;
      const f32x4* q = (const f32x4*)(x + (size_t)row * 1024 + kk);
      v0a = q[0]; v0b = q[1];
      a[0] = pack_bf16(v0a, v0b);
      ss0 += dot4(v0a) + dot4(v0b);
    }
    {
      const int row = r0 + 16 + m;
      const f32x4* q = (const f32x4*)(x + (size_t)row * 1024 + kk);
      v1a = q[0]; v1b = q[1];
      a[1] = pack_bf16(v1a, v1b);
      ss1 += dot4(v1a) + dot4(v1b);
    }
    if (wave == 0) {
      // exact fp32 copy of x -> input_flat (each tile element written once)
      float* d0 = out_flat + (size_t)(r0 + m) * 1024 + kk;
      float* d1 = out_flat + (size_t)(r0 + 16 + m) * 1024 + kk;
      *(f32x4*)d0 = v0a; *(f32x4*)(d0 + 4) = v0b;
      *(f32x4*)d1 = v1a; *(f32x4*)(d1 + 4) = v1b;
    }
    #pragma unroll
    for (int nf = 0; nf < 8; ++nf) {
      const bf16x8 b = *(const bf16x8*)(Mn + (size_t)(n0w + nf * 16 + m) * 1024 + kk);
      acc[nf][0] = __builtin_amdgcn_mfma_f32_16x16x32_bf16(a[0], b, acc[nf][0], 0, 0, 0);
      acc[nf][1] = __builtin_amdgcn_mfma_f32_16x16x32_bf16(a[1], b, acc[nf][1], 0, 0, 0);
    }
  }
  // reduce sumsq across quads (lanes with same m): xor 16, 32
  ss0 += __shfl_xor(ss0, 16); ss0 += __shfl_xor(ss0, 32);
  ss1 += __shfl_xor(ss1, 16); ss1 += __shfl_xor(ss1, 32);
  if (wave == 0 && quad == 0) {
    invn[m]      = 1.f / fmaxf(sqrtf(ss0), L2EPS);
    invn[16 + m] = 1.f / fmaxf(sqrtf(ss1), L2EPS);
  }
  // raw scores -> LDS
  #pragma unroll
  for (int nf = 0; nf < 8; ++nf)
    #pragma unroll
    for (int rg = 0; rg < 2; ++rg)
      #pragma unroll
      for (int vi = 0; vi < 4; ++vi)
        S[rg * 16 + quad * 4 + vi][n0w + nf * 16 + m] = acc[nf][rg][vi];
  __syncthreads();

  // per-row softmax over 512 (scaled by invn); 8 threads per row, skewed scan
  const int row = tid >> 3;
  const int sub = tid & 7;
  const float iv = invn[row];
  float mx = -1e30f;
  for (int i = 0; i < 64; ++i) {
    const int c = (sub + 4 * row + 8 * i) & 511;
    mx = fmaxf(mx, S[row][c]);
  }
  #pragma unroll
  for (int d = 1; d < 8; d <<= 1) mx = fmaxf(mx, __shfl_xor(mx, d));
  float se = 0.f;
  for (int i = 0; i < 64; ++i) {
    const int c = (sub + 4 * row + 8 * i) & 511;
    se += __expf((S[row][c] - mx) * iv);
  }
  #pragma unroll
  for (int d = 1; d < 8; d <<= 1) se += __shfl_xor(se, d);
  const float inv_se = 1.f / se;
  float rsum = 0.f;
  for (int i = 0; i < 64; ++i) {
    const int c = (sub + 4 * row + 8 * i) & 511;
    const float sh = fmaxf(__expf((S[row][c] - mx) * iv) * inv_se - SHRINKC, 0.f);
    S[row][c] = sh;
    rsum += sh;
  }
  #pragma unroll
  for (int d = 1; d < 8; d <<= 1) rsum += __shfl_xor(rsum, d);
  const float invr = 1.f / fmaxf(rsum, L2EPS);
  for (int i = 0; i < 64; ++i) {
    const int c = (sub + 4 * row + 8 * i) & 511;
    S[row][c] *= invr;
  }
  const int any = __syncthreads_or((sub == 0) && (rsum > 0.f));

  // write att rows (final values, zeros if fully shrunk)
  {
    float* dst = out_att + (size_t)r0 * 512;
    for (int idx = tid; idx < 32 * 512 / 4; idx += 256) {
      const int f = idx * 4;
      *(f32x4*)(dst + f) = *(const f32x4*)(&S[f >> 9][f & 511]);
    }
  }

  if (!any) {
    // fast path (data-driven): all rows shrunk to zero -> output rows are 0,
    // attsum contribution is 0.
    const f32x4 z = {0.f, 0.f, 0.f, 0.f};
    float* dst = out_out + (size_t)r0 * 1024;
    for (int idx = tid; idx < 32 * 1024 / 4; idx += 256)
      *(f32x4*)(dst + idx * 4) = z;
  } else {
    // general path: accumulate channel sums and compute att @ memory_norm
    const int nimg = r0 >> 9;  // rows r0..r0+31 share the same image index
    for (int c = tid; c < 512; c += 256) {
      float s = 0.f;
      for (int rr = 0; rr < 32; ++rr) s += S[rr][c];
      atomicAdd(&attsum[nimg * 512 + c], s);
    }
    const int c0 = tid * 4;
    for (int rr = 0; rr < 32; ++rr) {
      f32x4 o = {0.f, 0.f, 0.f, 0.f};
      for (int mm = 0; mm < 512; ++mm) {
        const float a = S[rr][mm];
        o += a * (*(const f32x4*)(Mnf + (size_t)mm * 1024 + c0));
      }
      *(f32x4*)(out_out + (size_t)(r0 + rr) * 1024 + c0) = o;
    }
  }
}

// ---- att_spatial broadcast: attsum/512 over 32x32 plane ------------------
// grid = 16384 (n*512+m), block = 256
__global__ __launch_bounds__(256) void spread(
    const float* __restrict__ attsum, float* __restrict__ out_sp) {
  const int nm = blockIdx.x;
  const float v = attsum[nm] * (1.f / 512.f);
  const f32x4 vv = {v, v, v, v};
  *(f32x4*)(out_sp + (size_t)nm * 1024 + threadIdx.x * 4) = vv;
}

// ---- launch --------------------------------------------------------------

extern "C" void kernel_launch(void* const* d_in, const int* in_sizes, int n_in,
                              void* d_out, int out_size, void* d_ws, size_t ws_size,
                              hipStream_t stream) {
  const float* x      = (const float*)d_in[0];  // 32*512*32*32
  const float* memory = (const float*)d_in[1];  // 512*1024
  const float* w1     = (const float*)d_in[2];  // 512*1024
  const float* b1     = (const float*)d_in[3];  // 512
  const float* w2     = (const float*)d_in[4];  // 1024*512
  const float* b2     = (const float*)d_in[5];  // 1024

  float* out = (float*)d_out;
  float* out_output = out;               // 16384*1024
  float* out_attsp  = out + 16777216;    // 32*512*1024
  float* out_flat   = out + 33554432;    // 16384*1024
  float* out_mnorm  = out + 50331648;    // 512*1024
  float* out_att    = out + 50855936;    // 16384*512

  char* ws = (char*)d_ws;
  float*  h      = (float*)ws;                         // 1 MB (512x512)
  __bf16* mnb    = (__bf16*)(ws + (1 << 20));          // 1 MB (512x1024 bf16)
  float*  attsum = (float*)(ws + (1 << 20) + (1 << 20)); // 64 KB

  gemm1<<<dim3(16, 16), 64, 0, stream>>>(memory, w1, b1, h, attsum);
  gemm2_norm<<<32, 256, 0, stream>>>(h, w2, b2, out_mnorm, mnb);
  attend<<<512, 256, 0, stream>>>(x, mnb, out_mnorm, out_flat, out_output, out_att, attsum);
  spread<<<16384, 256, 0, stream>>>(attsum, out_attsp);
}

// Round 4
// 462.774 us; speedup vs baseline: 1.0040x; 1.0040x over previous
//
#include <hip/hip_runtime.h>

typedef float  f32x4  __attribute__((ext_vector_type(4)));
typedef __bf16 bf16x8 __attribute__((ext_vector_type(8)));
typedef __bf16 bf16x4 __attribute__((ext_vector_type(4)));

#define L2EPS   1e-12f
#define SHRINKC 0.0025f

// ---- helpers -------------------------------------------------------------

__device__ __forceinline__ bf16x8 pack_bf16(f32x4 v0, f32x4 v1) {
  bf16x8 r;
  r[0] = (__bf16)v0[0]; r[1] = (__bf16)v0[1]; r[2] = (__bf16)v0[2]; r[3] = (__bf16)v0[3];
  r[4] = (__bf16)v1[0]; r[5] = (__bf16)v1[1]; r[6] = (__bf16)v1[2]; r[7] = (__bf16)v1[3];
  return r;
}

__device__ __forceinline__ bf16x8 load_cvt_bf16x8(const float* p) {
  const f32x4* q = (const f32x4*)p;
  return pack_bf16(q[0], q[1]);
}

__device__ __forceinline__ float dot4(f32x4 v) {
  return v[0]*v[0] + v[1]*v[1] + v[2]*v[2] + v[3]*v[3];
}

// ---- gemm1: h = relu(memory @ w1^T + b1), 32x32 tile / 1-wave block ------
// grid = (16,16), block = 64. Also zeroes attsum (64 floats per block).
__global__ __launch_bounds__(64) void gemm1(
    const float* __restrict__ A, const float* __restrict__ B,
    const float* __restrict__ bias, float* __restrict__ C,
    float* __restrict__ attsum) {
  const int bid = blockIdx.y * gridDim.x + blockIdx.x;  // 0..255
  attsum[bid * 64 + threadIdx.x] = 0.f;

  const int K = 1024, N = 512;
  const int r0   = blockIdx.x * 32;
  const int n0   = blockIdx.y * 32;
  const int lane = threadIdx.x & 63;
  const int quad = lane >> 4;
  const int m    = lane & 15;

  f32x4 acc[2][2] = {};
  for (int k0 = 0; k0 < K; k0 += 32) {
    const int kk = k0 + quad * 8;
    bf16x8 a[2], b[2];
    #pragma unroll
    for (int rg = 0; rg < 2; ++rg)
      a[rg] = load_cvt_bf16x8(A + (size_t)(r0 + rg * 16 + m) * K + kk);
    #pragma unroll
    for (int cf = 0; cf < 2; ++cf)
      b[cf] = load_cvt_bf16x8(B + (size_t)(n0 + cf * 16 + m) * K + kk);
    #pragma unroll
    for (int rg = 0; rg < 2; ++rg)
      #pragma unroll
      for (int cf = 0; cf < 2; ++cf)
        acc[rg][cf] = __builtin_amdgcn_mfma_f32_16x16x32_bf16(a[rg], b[cf], acc[rg][cf], 0, 0, 0);
  }
  #pragma unroll
  for (int rg = 0; rg < 2; ++rg)
    #pragma unroll
    for (int cf = 0; cf < 2; ++cf) {
      const int n = n0 + cf * 16 + m;
      const float bv = bias[n];
      #pragma unroll
      for (int vi = 0; vi < 4; ++vi) {
        const int r = r0 + rg * 16 + quad * 4 + vi;
        C[(size_t)r * N + n] = fmaxf(acc[rg][cf][vi] + bv, 0.f);
      }
    }
}

// ---- gemm2_norm: mp = relu(h @ w2^T + b2); memory_norm = l2norm(mp) ------
// Full-row tiles: grid = 32 (16 rows each), block = 256 (4 waves x 256 cols).
// Writes mnorm fp32 (output 3) + bf16 copy; mp never hits memory.
__global__ __launch_bounds__(256) void gemm2_norm(
    const float* __restrict__ A,    // h: 512 x 512
    const float* __restrict__ B,    // w2: 1024 x 512
    const float* __restrict__ bias, // b2: 1024
    float* __restrict__ mn_f32, __bf16* __restrict__ mn_bf16) {
  const int r0   = blockIdx.x * 16;
  const int wave = threadIdx.x >> 6;
  const int lane = threadIdx.x & 63;
  const int quad = lane >> 4;
  const int m    = lane & 15;
  const int n0   = wave * 256;

  f32x4 acc[16] = {};
  for (int k0 = 0; k0 < 512; k0 += 32) {
    const int kk = k0 + quad * 8;
    const bf16x8 a = load_cvt_bf16x8(A + (size_t)(r0 + m) * 512 + kk);
    #pragma unroll
    for (int cf = 0; cf < 16; ++cf) {
      const bf16x8 b = load_cvt_bf16x8(B + (size_t)(n0 + cf * 16 + m) * 512 + kk);
      acc[cf] = __builtin_amdgcn_mfma_f32_16x16x32_bf16(a, b, acc[cf], 0, 0, 0);
    }
  }
  // bias + relu, per-row sumsq partials (lane holds rows quad*4+vi, 16 cols)
  float ss[4] = {0.f, 0.f, 0.f, 0.f};
  #pragma unroll
  for (int cf = 0; cf < 16; ++cf) {
    const float bv = bias[n0 + cf * 16 + m];
    #pragma unroll
    for (int vi = 0; vi < 4; ++vi) {
      const float v = fmaxf(acc[cf][vi] + bv, 0.f);
      acc[cf][vi] = v;
      ss[vi] += v * v;
    }
  }
  // reduce over the 16 m-lanes within each quad
  #pragma unroll
  for (int vi = 0; vi < 4; ++vi)
    #pragma unroll
    for (int d = 1; d < 16; d <<= 1) ss[vi] += __shfl_xor(ss[vi], d);

  __shared__ float psum[4][16];
  __shared__ float invs[16];
  if (m == 0) {
    #pragma unroll
    for (int vi = 0; vi < 4; ++vi) psum[wave][quad * 4 + vi] = ss[vi];
  }
  __syncthreads();
  if (threadIdx.x < 16) {
    const float t = psum[0][threadIdx.x] + psum[1][threadIdx.x] +
                    psum[2][threadIdx.x] + psum[3][threadIdx.x];
    invs[threadIdx.x] = 1.f / fmaxf(sqrtf(t), L2EPS);
  }
  __syncthreads();
  #pragma unroll
  for (int vi = 0; vi < 4; ++vi) {
    const int r = r0 + quad * 4 + vi;
    const float iv = invs[quad * 4 + vi];
    #pragma unroll
    for (int cf = 0; cf < 16; ++cf) {
      const int n = n0 + cf * 16 + m;
      const float o = acc[cf][vi] * iv;
      mn_f32[(size_t)r * 1024 + n] = o;
      mn_bf16[(size_t)r * 1024 + n] = (__bf16)o;
    }
  }
}

// ---- fused attention: copies x -> input_flat, computes row norms inline,
//      scores -> softmax (no max-shift: cosine in [-1,1]) -> shrink ->
//      renorm -> att/output/attsum ----------------------------------------
// grid = 512 (32 rows each), block = 256 (4 waves; wave w owns cols w*128..)
__global__ __launch_bounds__(256) void attend(
    const float* __restrict__ x, const __bf16* __restrict__ Mn,
    const float* __restrict__ Mnf, float* __restrict__ out_flat,
    float* __restrict__ out_out, float* __restrict__ out_att,
    float* __restrict__ attsum) {
  __shared__ float S[32][512];  // 64 KB
  __shared__ float invn[32];
  const int r0   = blockIdx.x * 32;
  const int tid  = threadIdx.x;
  const int wave = tid >> 6;
  const int lane = tid & 63;
  const int quad = lane >> 4;
  const int m    = lane & 15;
  const int n0w  = wave * 128;

  float ss0 = 0.f, ss1 = 0.f;
  f32x4 acc[8][2] = {};
  for (int k0 = 0; k0 < 1024; k0 += 32) {
    const int kk = k0 + quad * 8;
    bf16x8 a[2];
    f32x4 v0a, v0b, v1a, v1b;
    {
      const int row = r0 + m;
      const f32x4* q = (const f32x4*)(x + (size_t)row * 1024 + kk);
      v0a = q[0]; v0b = q[1];
      a[0] = pack_bf16(v0a, v0b);
      ss0 += dot4(v0a) + dot4(v0b);
    }
    {
      const int row = r0 + 16 + m;
      const f32x4* q = (const f32x4*)(x + (size_t)row * 1024 + kk);
      v1a = q[0]; v1b = q[1];
      a[1] = pack_bf16(v1a, v1b);
      ss1 += dot4(v1a) + dot4(v1b);
    }
    if (wave == 0) {
      // exact fp32 copy of x -> input_flat (each tile element written once)
      float* d0 = out_flat + (size_t)(r0 + m) * 1024 + kk;
      float* d1 = out_flat + (size_t)(r0 + 16 + m) * 1024 + kk;
      *(f32x4*)d0 = v0a; *(f32x4*)(d0 + 4) = v0b;
      *(f32x4*)d1 = v1a; *(f32x4*)(d1 + 4) = v1b;
    }
    #pragma unroll
    for (int nf = 0; nf < 8; ++nf) {
      const bf16x8 b = *(const bf16x8*)(Mn + (size_t)(n0w + nf * 16 + m) * 1024 + kk);
      acc[nf][0] = __builtin_amdgcn_mfma_f32_16x16x32_bf16(a[0], b, acc[nf][0], 0, 0, 0);
      acc[nf][1] = __builtin_amdgcn_mfma_f32_16x16x32_bf16(a[1], b, acc[nf][1], 0, 0, 0);
    }
  }
  // reduce sumsq across quads (lanes with same m): xor 16, 32
  ss0 += __shfl_xor(ss0, 16); ss0 += __shfl_xor(ss0, 32);
  ss1 += __shfl_xor(ss1, 16); ss1 += __shfl_xor(ss1, 32);
  if (wave == 0 && quad == 0) {
    invn[m]      = 1.f / fmaxf(sqrtf(ss0), L2EPS);
    invn[16 + m] = 1.f / fmaxf(sqrtf(ss1), L2EPS);
  }
  // raw scores -> LDS
  #pragma unroll
  for (int nf = 0; nf < 8; ++nf)
    #pragma unroll
    for (int rg = 0; rg < 2; ++rg)
      #pragma unroll
      for (int vi = 0; vi < 4; ++vi)
        S[rg * 16 + quad * 4 + vi][n0w + nf * 16 + m] = acc[nf][rg][vi];
  __syncthreads();

  // per-row softmax over 512; 8 threads per row, bank-skewed scan.
  // No max-subtraction: scores*invn are cosines in [-1,1] (softmax is
  // shift-invariant; exp cannot overflow).
  const int row = tid >> 3;
  const int sub = tid & 7;
  const float iv = invn[row];
  float se = 0.f;
  for (int i = 0; i < 64; ++i) {
    const int c = (sub + 4 * row + 8 * i) & 511;
    const float e = __expf(S[row][c] * iv);
    S[row][c] = e;
    se += e;
  }
  #pragma unroll
  for (int d = 1; d < 8; d <<= 1) se += __shfl_xor(se, d);
  const float inv_se = 1.f / se;
  float rsum = 0.f;
  for (int i = 0; i < 64; ++i) {
    const int c = (sub + 4 * row + 8 * i) & 511;
    const float sh = fmaxf(S[row][c] * inv_se - SHRINKC, 0.f);
    S[row][c] = sh;
    rsum += sh;
  }
  #pragma unroll
  for (int d = 1; d < 8; d <<= 1) rsum += __shfl_xor(rsum, d);
  const float invr = 1.f / fmaxf(rsum, L2EPS);
  for (int i = 0; i < 64; ++i) {
    const int c = (sub + 4 * row + 8 * i) & 511;
    S[row][c] *= invr;
  }
  const int any = __syncthreads_or((sub == 0) && (rsum > 0.f));

  // write att rows (final values, zeros if fully shrunk)
  {
    float* dst = out_att + (size_t)r0 * 512;
    for (int idx = tid; idx < 32 * 512 / 4; idx += 256) {
      const int f = idx * 4;
      *(f32x4*)(dst + f) = *(const f32x4*)(&S[f >> 9][f & 511]);
    }
  }

  if (!any) {
    // fast path (data-driven): all rows shrunk to zero -> output rows are 0,
    // attsum contribution is 0.
    const f32x4 z = {0.f, 0.f, 0.f, 0.f};
    float* dst = out_out + (size_t)r0 * 1024;
    for (int idx = tid; idx < 32 * 1024 / 4; idx += 256)
      *(f32x4*)(dst + idx * 4) = z;
  } else {
    // general path: accumulate channel sums and compute att @ memory_norm
    const int nimg = r0 >> 9;  // rows r0..r0+31 share the same image index
    for (int c = tid; c < 512; c += 256) {
      float s = 0.f;
      for (int rr = 0; rr < 32; ++rr) s += S[rr][c];
      atomicAdd(&attsum[nimg * 512 + c], s);
    }
    const int c0 = tid * 4;
    for (int rr = 0; rr < 32; ++rr) {
      f32x4 o = {0.f, 0.f, 0.f, 0.f};
      for (int mm = 0; mm < 512; ++mm) {
        const float a = S[rr][mm];
        o += a * (*(const f32x4*)(Mnf + (size_t)mm * 1024 + c0));
      }
      *(f32x4*)(out_out + (size_t)(r0 + rr) * 1024 + c0) = o;
    }
  }
}

// ---- att_spatial broadcast: attsum/512 over 32x32 plane ------------------
// grid = 16384 (n*512+m), block = 256
__global__ __launch_bounds__(256) void spread(
    const float* __restrict__ attsum, float* __restrict__ out_sp) {
  const int nm = blockIdx.x;
  const float v = attsum[nm] * (1.f / 512.f);
  const f32x4 vv = {v, v, v, v};
  *(f32x4*)(out_sp + (size_t)nm * 1024 + threadIdx.x * 4) = vv;
}

// ---- launch --------------------------------------------------------------

extern "C" void kernel_launch(void* const* d_in, const int* in_sizes, int n_in,
                              void* d_out, int out_size, void* d_ws, size_t ws_size,
                              hipStream_t stream) {
  const float* x      = (const float*)d_in[0];  // 32*512*32*32
  const float* memory = (const float*)d_in[1];  // 512*1024
  const float* w1     = (const float*)d_in[2];  // 512*1024
  const float* b1     = (const float*)d_in[3];  // 512
  const float* w2     = (const float*)d_in[4];  // 1024*512
  const float* b2     = (const float*)d_in[5];  // 1024

  float* out = (float*)d_out;
  float* out_output = out;               // 16384*1024
  float* out_attsp  = out + 16777216;    // 32*512*1024
  float* out_flat   = out + 33554432;    // 16384*1024
  float* out_mnorm  = out + 50331648;    // 512*1024
  float* out_att    = out + 50855936;    // 16384*512

  char* ws = (char*)d_ws;
  float*  h      = (float*)ws;                         // 1 MB (512x512)
  __bf16* mnb    = (__bf16*)(ws + (1 << 20));          // 1 MB (512x1024 bf16)
  float*  attsum = (float*)(ws + (1 << 20) + (1 << 20)); // 64 KB

  gemm1<<<dim3(16, 16), 64, 0, stream>>>(memory, w1, b1, h, attsum);
  gemm2_norm<<<32, 256, 0, stream>>>(h, w2, b2, out_mnorm, mnb);
  attend<<<512, 256, 0, stream>>>(x, mnb, out_mnorm, out_flat, out_output, out_att, attsum);
  spread<<<16384, 256, 0, stream>>>(attsum, out_attsp);
}

// Round 5
// 416.617 us; speedup vs baseline: 1.1153x; 1.1108x over previous
//
#include <hip/hip_runtime.h>

typedef float  f32x4  __attribute__((ext_vector_type(4)));
typedef __bf16 bf16x8 __attribute__((ext_vector_type(8)));
typedef __bf16 bf16x4 __attribute__((ext_vector_type(4)));

#define L2EPS   1e-12f
#define SHRINKC 0.0025f

// ---- helpers -------------------------------------------------------------

__device__ __forceinline__ bf16x8 pack_bf16(f32x4 v0, f32x4 v1) {
  bf16x8 r;
  r[0] = (__bf16)v0[0]; r[1] = (__bf16)v0[1]; r[2] = (__bf16)v0[2]; r[3] = (__bf16)v0[3];
  r[4] = (__bf16)v1[0]; r[5] = (__bf16)v1[1]; r[6] = (__bf16)v1[2]; r[7] = (__bf16)v1[3];
  return r;
}

__device__ __forceinline__ bf16x8 load_cvt_bf16x8(const float* p) {
  const f32x4* q = (const f32x4*)p;
  return pack_bf16(q[0], q[1]);
}

__device__ __forceinline__ float dot4(f32x4 v) {
  return v[0]*v[0] + v[1]*v[1] + v[2]*v[2] + v[3]*v[3];
}

// ---- gemm1: h = relu(memory @ w1^T + b1), 32x32 tile / 1-wave block ------
// grid = (16,16), block = 64. Also zeroes attsum (64 floats per block).
__global__ __launch_bounds__(64) void gemm1(
    const float* __restrict__ A, const float* __restrict__ B,
    const float* __restrict__ bias, float* __restrict__ C,
    float* __restrict__ attsum) {
  const int bid = blockIdx.y * gridDim.x + blockIdx.x;  // 0..255
  attsum[bid * 64 + threadIdx.x] = 0.f;

  const int K = 1024, N = 512;
  const int r0   = blockIdx.x * 32;
  const int n0   = blockIdx.y * 32;
  const int lane = threadIdx.x & 63;
  const int quad = lane >> 4;
  const int m    = lane & 15;

  f32x4 acc[2][2] = {};
  for (int k0 = 0; k0 < K; k0 += 32) {
    const int kk = k0 + quad * 8;
    bf16x8 a[2], b[2];
    #pragma unroll
    for (int rg = 0; rg < 2; ++rg)
      a[rg] = load_cvt_bf16x8(A + (size_t)(r0 + rg * 16 + m) * K + kk);
    #pragma unroll
    for (int cf = 0; cf < 2; ++cf)
      b[cf] = load_cvt_bf16x8(B + (size_t)(n0 + cf * 16 + m) * K + kk);
    #pragma unroll
    for (int rg = 0; rg < 2; ++rg)
      #pragma unroll
      for (int cf = 0; cf < 2; ++cf)
        acc[rg][cf] = __builtin_amdgcn_mfma_f32_16x16x32_bf16(a[rg], b[cf], acc[rg][cf], 0, 0, 0);
  }
  #pragma unroll
  for (int rg = 0; rg < 2; ++rg)
    #pragma unroll
    for (int cf = 0; cf < 2; ++cf) {
      const int n = n0 + cf * 16 + m;
      const float bv = bias[n];
      #pragma unroll
      for (int vi = 0; vi < 4; ++vi) {
        const int r = r0 + rg * 16 + quad * 4 + vi;
        C[(size_t)r * N + n] = fmaxf(acc[rg][cf][vi] + bv, 0.f);
      }
    }
}

// ---- gemm2: mp = relu(h @ w2^T + b2), 32x32 tile / 1-wave block ----------
// grid = (16, 32), block = 64. Low register pressure (2x2 acc), 512 blocks.
__global__ __launch_bounds__(64) void gemm2(
    const float* __restrict__ A, const float* __restrict__ B,
    const float* __restrict__ bias, float* __restrict__ C) {
  const int K = 512, N = 1024;
  const int r0   = blockIdx.x * 32;
  const int n0   = blockIdx.y * 32;
  const int lane = threadIdx.x & 63;
  const int quad = lane >> 4;
  const int m    = lane & 15;

  f32x4 acc[2][2] = {};
  for (int k0 = 0; k0 < K; k0 += 32) {
    const int kk = k0 + quad * 8;
    bf16x8 a[2], b[2];
    #pragma unroll
    for (int rg = 0; rg < 2; ++rg)
      a[rg] = load_cvt_bf16x8(A + (size_t)(r0 + rg * 16 + m) * K + kk);
    #pragma unroll
    for (int cf = 0; cf < 2; ++cf)
      b[cf] = load_cvt_bf16x8(B + (size_t)(n0 + cf * 16 + m) * K + kk);
    #pragma unroll
    for (int rg = 0; rg < 2; ++rg)
      #pragma unroll
      for (int cf = 0; cf < 2; ++cf)
        acc[rg][cf] = __builtin_amdgcn_mfma_f32_16x16x32_bf16(a[rg], b[cf], acc[rg][cf], 0, 0, 0);
  }
  #pragma unroll
  for (int rg = 0; rg < 2; ++rg)
    #pragma unroll
    for (int cf = 0; cf < 2; ++cf) {
      const int n = n0 + cf * 16 + m;
      const float bv = bias[n];
      #pragma unroll
      for (int vi = 0; vi < 4; ++vi) {
        const int r = r0 + rg * 16 + quad * 4 + vi;
        C[(size_t)r * N + n] = fmaxf(acc[rg][cf][vi] + bv, 0.f);
      }
    }
}

// ---- normalize mem_proc rows -> memory_norm (fp32 out + bf16 ws copy) ----
// grid = 512, block = 256
__global__ __launch_bounds__(256) void norm_rows(
    const float* __restrict__ mp, float* __restrict__ mn_f32,
    __bf16* __restrict__ mn_bf16) {
  const int r = blockIdx.x;
  const int tid = threadIdx.x;
  const f32x4 v = *(const f32x4*)(mp + (size_t)r * 1024 + tid * 4);
  float ss = dot4(v);
  #pragma unroll
  for (int d = 1; d < 64; d <<= 1) ss += __shfl_xor(ss, d);
  __shared__ float wsum[4];
  __shared__ float invs;
  if ((tid & 63) == 0) wsum[tid >> 6] = ss;
  __syncthreads();
  if (tid == 0) {
    float t = wsum[0] + wsum[1] + wsum[2] + wsum[3];
    invs = 1.f / fmaxf(sqrtf(t), L2EPS);
  }
  __syncthreads();
  const float iv = invs;
  f32x4 o = v * iv;
  *(f32x4*)(mn_f32 + (size_t)r * 1024 + tid * 4) = o;
  bf16x4 ob;
  ob[0] = (__bf16)o[0]; ob[1] = (__bf16)o[1]; ob[2] = (__bf16)o[2]; ob[3] = (__bf16)o[3];
  *(bf16x4*)(mn_bf16 + (size_t)r * 1024 + tid * 4) = ob;
}

// ---- fused attention: copies x -> input_flat, computes row norms inline,
//      scores -> softmax (no max-shift: cosine in [-1,1]) -> shrink ->
//      renorm -> att/output/attsum ----------------------------------------
// grid = 512 (32 rows each), block = 256 (4 waves; wave w owns cols w*128..)
__global__ __launch_bounds__(256) void attend(
    const float* __restrict__ x, const __bf16* __restrict__ Mn,
    const float* __restrict__ Mnf, float* __restrict__ out_flat,
    float* __restrict__ out_out, float* __restrict__ out_att,
    float* __restrict__ attsum) {
  __shared__ float S[32][512];  // 64 KB
  __shared__ float invn[32];
  const int r0   = blockIdx.x * 32;
  const int tid  = threadIdx.x;
  const int wave = tid >> 6;
  const int lane = tid & 63;
  const int quad = lane >> 4;
  const int m    = lane & 15;
  const int n0w  = wave * 128;

  float ss0 = 0.f, ss1 = 0.f;
  f32x4 acc[8][2] = {};
  for (int k0 = 0; k0 < 1024; k0 += 32) {
    const int kk = k0 + quad * 8;
    bf16x8 a[2];
    f32x4 v0a, v0b, v1a, v1b;
    {
      const int row = r0 + m;
      const f32x4* q = (const f32x4*)(x + (size_t)row * 1024 + kk);
      v0a = q[0]; v0b = q[1];
      a[0] = pack_bf16(v0a, v0b);
      ss0 += dot4(v0a) + dot4(v0b);
    }
    {
      const int row = r0 + 16 + m;
      const f32x4* q = (const f32x4*)(x + (size_t)row * 1024 + kk);
      v1a = q[0]; v1b = q[1];
      a[1] = pack_bf16(v1a, v1b);
      ss1 += dot4(v1a) + dot4(v1b);
    }
    if (wave == 0) {
      // exact fp32 copy of x -> input_flat (each tile element written once)
      float* d0 = out_flat + (size_t)(r0 + m) * 1024 + kk;
      float* d1 = out_flat + (size_t)(r0 + 16 + m) * 1024 + kk;
      *(f32x4*)d0 = v0a; *(f32x4*)(d0 + 4) = v0b;
      *(f32x4*)d1 = v1a; *(f32x4*)(d1 + 4) = v1b;
    }
    #pragma unroll
    for (int nf = 0; nf < 8; ++nf) {
      const bf16x8 b = *(const bf16x8*)(Mn + (size_t)(n0w + nf * 16 + m) * 1024 + kk);
      acc[nf][0] = __builtin_amdgcn_mfma_f32_16x16x32_bf16(a[0], b, acc[nf][0], 0, 0, 0);
      acc[nf][1] = __builtin_amdgcn_mfma_f32_16x16x32_bf16(a[1], b, acc[nf][1], 0, 0, 0);
    }
  }
  // reduce sumsq across quads (lanes with same m): xor 16, 32
  ss0 += __shfl_xor(ss0, 16); ss0 += __shfl_xor(ss0, 32);
  ss1 += __shfl_xor(ss1, 16); ss1 += __shfl_xor(ss1, 32);
  if (wave == 0 && quad == 0) {
    invn[m]      = 1.f / fmaxf(sqrtf(ss0), L2EPS);
    invn[16 + m] = 1.f / fmaxf(sqrtf(ss1), L2EPS);
  }
  // raw scores -> LDS
  #pragma unroll
  for (int nf = 0; nf < 8; ++nf)
    #pragma unroll
    for (int rg = 0; rg < 2; ++rg)
      #pragma unroll
      for (int vi = 0; vi < 4; ++vi)
        S[rg * 16 + quad * 4 + vi][n0w + nf * 16 + m] = acc[nf][rg][vi];
  __syncthreads();

  // per-row softmax over 512; 8 threads per row, bank-skewed scan.
  // No max-subtraction: scores*invn are cosines in [-1,1] (softmax is
  // shift-invariant; exp cannot overflow).
  const int row = tid >> 3;
  const int sub = tid & 7;
  const float iv = invn[row];
  float se = 0.f;
  for (int i = 0; i < 64; ++i) {
    const int c = (sub + 4 * row + 8 * i) & 511;
    const float e = __expf(S[row][c] * iv);
    S[row][c] = e;
    se += e;
  }
  #pragma unroll
  for (int d = 1; d < 8; d <<= 1) se += __shfl_xor(se, d);
  const float inv_se = 1.f / se;
  float rsum = 0.f;
  for (int i = 0; i < 64; ++i) {
    const int c = (sub + 4 * row + 8 * i) & 511;
    const float sh = fmaxf(S[row][c] * inv_se - SHRINKC, 0.f);
    S[row][c] = sh;
    rsum += sh;
  }
  #pragma unroll
  for (int d = 1; d < 8; d <<= 1) rsum += __shfl_xor(rsum, d);
  const float invr = 1.f / fmaxf(rsum, L2EPS);
  for (int i = 0; i < 64; ++i) {
    const int c = (sub + 4 * row + 8 * i) & 511;
    S[row][c] *= invr;
  }
  const int any = __syncthreads_or((sub == 0) && (rsum > 0.f));

  // write att rows (final values, zeros if fully shrunk)
  {
    float* dst = out_att + (size_t)r0 * 512;
    for (int idx = tid; idx < 32 * 512 / 4; idx += 256) {
      const int f = idx * 4;
      *(f32x4*)(dst + f) = *(const f32x4*)(&S[f >> 9][f & 511]);
    }
  }

  if (!any) {
    // fast path (data-driven): all rows shrunk to zero -> output rows are 0,
    // attsum contribution is 0.
    const f32x4 z = {0.f, 0.f, 0.f, 0.f};
    float* dst = out_out + (size_t)r0 * 1024;
    for (int idx = tid; idx < 32 * 1024 / 4; idx += 256)
      *(f32x4*)(dst + idx * 4) = z;
  } else {
    // general path: accumulate channel sums and compute att @ memory_norm
    const int nimg = r0 >> 9;  // rows r0..r0+31 share the same image index
    for (int c = tid; c < 512; c += 256) {
      float s = 0.f;
      for (int rr = 0; rr < 32; ++rr) s += S[rr][c];
      atomicAdd(&attsum[nimg * 512 + c], s);
    }
    const int c0 = tid * 4;
    for (int rr = 0; rr < 32; ++rr) {
      f32x4 o = {0.f, 0.f, 0.f, 0.f};
      for (int mm = 0; mm < 512; ++mm) {
        const float a = S[rr][mm];
        o += a * (*(const f32x4*)(Mnf + (size_t)mm * 1024 + c0));
      }
      *(f32x4*)(out_out + (size_t)(r0 + rr) * 1024 + c0) = o;
    }
  }
}

// ---- att_spatial broadcast: attsum/512 over 32x32 plane ------------------
// grid = 16384 (n*512+m), block = 256
__global__ __launch_bounds__(256) void spread(
    const float* __restrict__ attsum, float* __restrict__ out_sp) {
  const int nm = blockIdx.x;
  const float v = attsum[nm] * (1.f / 512.f);
  const f32x4 vv = {v, v, v, v};
  *(f32x4*)(out_sp + (size_t)nm * 1024 + threadIdx.x * 4) = vv;
}

// ---- launch --------------------------------------------------------------

extern "C" void kernel_launch(void* const* d_in, const int* in_sizes, int n_in,
                              void* d_out, int out_size, void* d_ws, size_t ws_size,
                              hipStream_t stream) {
  const float* x      = (const float*)d_in[0];  // 32*512*32*32
  const float* memory = (const float*)d_in[1];  // 512*1024
  const float* w1     = (const float*)d_in[2];  // 512*1024
  const float* b1     = (const float*)d_in[3];  // 512
  const float* w2     = (const float*)d_in[4];  // 1024*512
  const float* b2     = (const float*)d_in[5];  // 1024

  float* out = (float*)d_out;
  float* out_output = out;               // 16384*1024
  float* out_attsp  = out + 16777216;    // 32*512*1024
  float* out_flat   = out + 33554432;    // 16384*1024
  float* out_mnorm  = out + 50331648;    // 512*1024
  float* out_att    = out + 50855936;    // 16384*512

  char* ws = (char*)d_ws;
  float*  h      = (float*)ws;                                  // 1 MB (512x512)
  float*  mp     = (float*)(ws + (1 << 20));                    // 2 MB (512x1024)
  __bf16* mnb    = (__bf16*)(ws + (1 << 20) + (2 << 20));       // 1 MB
  float*  attsum = (float*)(ws + (1 << 20) + (2 << 20) + (1 << 20)); // 64 KB

  gemm1<<<dim3(16, 16), 64, 0, stream>>>(memory, w1, b1, h, attsum);
  gemm2<<<dim3(16, 32), 64, 0, stream>>>(h, w2, b2, mp);
  norm_rows<<<512, 256, 0, stream>>>(mp, out_mnorm, mnb);
  attend<<<512, 256, 0, stream>>>(x, mnb, out_mnorm, out_flat, out_output, out_att, attsum);
  spread<<<16384, 256, 0, stream>>>(attsum, out_attsp);
}